// Round 1
// baseline (260034.106 us; speedup 1.0000x reference)
//
#include <hip/hip_runtime.h>
#include <hip/hip_bf16.h>
#include <stdint.h>

#define SEQ_LEN 65536
#define NCHARS  512
#define EMB     512
#define HID     1024

typedef unsigned long long u64;

// ---------------------------------------------------------------------------
// Kernel 1: XP_table[ch][i] = sum_e emb[ch][e] * Wax[i][e]   (512 x 1024)
// Also zero-initializes the h pair buffer (tag 0 == h_0 = 0).
// 128 blocks x 4 chars, 256 threads.
// ---------------------------------------------------------------------------
__global__ __launch_bounds__(256) void xp_table_kernel(
    const float* __restrict__ emb, const float* __restrict__ Wax,
    float* __restrict__ XP, u64* __restrict__ hbufP)
{
    __shared__ float elds[4 * EMB];
    const int bx  = blockIdx.x;
    const int tid = threadIdx.x;
    const int ch0 = bx * 4;

    const float4* src = (const float4*)(emb + (size_t)ch0 * EMB);
    float4* dst = (float4*)elds;
    dst[tid]       = src[tid];
    dst[tid + 256] = src[tid + 256];

    if (bx == 0) {
        #pragma unroll
        for (int j = 0; j < 8; ++j) hbufP[tid * 8 + j] = 0ull;
    }
    __syncthreads();

    float acc[4][4] = {};
    for (int e4 = 0; e4 < EMB / 4; ++e4) {
        float4 ev[4];
        #pragma unroll
        for (int ch = 0; ch < 4; ++ch) ev[ch] = *(const float4*)&elds[ch * EMB + 4 * e4];
        #pragma unroll
        for (int q = 0; q < 4; ++q) {
            const int i = tid + 256 * q;
            float4 w4 = *(const float4*)&Wax[(size_t)i * EMB + 4 * e4];
            #pragma unroll
            for (int ch = 0; ch < 4; ++ch) {
                acc[ch][q] = fmaf(w4.x, ev[ch].x, acc[ch][q]);
                acc[ch][q] = fmaf(w4.y, ev[ch].y, acc[ch][q]);
                acc[ch][q] = fmaf(w4.z, ev[ch].z, acc[ch][q]);
                acc[ch][q] = fmaf(w4.w, ev[ch].w, acc[ch][q]);
            }
        }
    }
    #pragma unroll
    for (int ch = 0; ch < 4; ++ch)
        #pragma unroll
        for (int q = 0; q < 4; ++q)
            XP[(size_t)(ch0 + ch) * HID + tid + 256 * q] = acc[ch][q];
}

// ---------------------------------------------------------------------------
// Kernel 2: the sequential scan.  64 blocks x 256 threads (4 waves).
// Block b owns rows [b*16, b*16+16) of Waa, held in registers:
//   thread (wave wv, lane l): rows b*16+wv*4+i (i<4), cols l*16..l*16+15.
// Cross-block h exchange: hbufP[parity][row] = {tag(g+1) << 32 | f32 bits},
// single 8B SYSTEM-scope atomic store/load (served at LLC, cross-XCD safe).
// Double-buffered by step parity; poll-on-data => no separate flags/fences.
// ---------------------------------------------------------------------------
__global__ __launch_bounds__(256) void scan_kernel(
    const int* __restrict__ seq, const float* __restrict__ XP,
    const float* __restrict__ Waa, u64* __restrict__ hbufP,
    float* __restrict__ hs, int g0, int Sc,
    float* __restrict__ out_tail, int is_last)
{
    __shared__ float h_lds[HID];
    __shared__ int   seq_lds[256];

    const int b   = blockIdx.x;        // 0..63
    const int tid = threadIdx.x;       // 0..255
    const int l   = tid & 63;          // lane in wave
    const int wv  = tid >> 6;          // wave 0..3
    const int r2  = (l >> 1) & 3;      // float4 rotation -> 8 distinct LDS bank quads

    // Load Waa slice into registers (rotated so inner loop uses static indices).
    float4 w4[4][4];
    #pragma unroll
    for (int i = 0; i < 4; ++i) {
        const float* wrow = Waa + (size_t)(b * 16 + wv * 4 + i) * HID + l * 16;
        #pragma unroll
        for (int u = 0; u < 4; ++u)
            w4[i][u] = *(const float4*)(wrow + 4 * ((u + r2) & 3));
    }

    for (int t = 0; t < Sc; ++t) {
        const int g = g0 + t;
        // ---- poll h_g (tagged pairs), rows 4*tid..4*tid+3 ----
        {
            u64* hb = hbufP + (size_t)(g & 1) * HID + 4 * tid;
            const unsigned want = (unsigned)g;
            u64 v0, v1, v2, v3;
            do {
                v0 = __hip_atomic_load(hb + 0, __ATOMIC_RELAXED, __HIP_MEMORY_SCOPE_SYSTEM);
                v1 = __hip_atomic_load(hb + 1, __ATOMIC_RELAXED, __HIP_MEMORY_SCOPE_SYSTEM);
                v2 = __hip_atomic_load(hb + 2, __ATOMIC_RELAXED, __HIP_MEMORY_SCOPE_SYSTEM);
                v3 = __hip_atomic_load(hb + 3, __ATOMIC_RELAXED, __HIP_MEMORY_SCOPE_SYSTEM);
            } while (((unsigned)(v0 >> 32) != want) | ((unsigned)(v1 >> 32) != want) |
                     ((unsigned)(v2 >> 32) != want) | ((unsigned)(v3 >> 32) != want));
            float4 hv = make_float4(__uint_as_float((unsigned)v0), __uint_as_float((unsigned)v1),
                                    __uint_as_float((unsigned)v2), __uint_as_float((unsigned)v3));
            *(float4*)&h_lds[4 * tid] = hv;
        }
        if ((t & 255) == 0) seq_lds[tid] = seq[g + tid];  // g is a multiple of 256 here
        __syncthreads();

        // ---- partial dot products: 4 rows x own 16 cols ----
        float4 h4[4];
        #pragma unroll
        for (int u = 0; u < 4; ++u)
            h4[u] = *(float4*)&h_lds[l * 16 + 4 * ((u + r2) & 3)];
        float acc[4] = {0.f, 0.f, 0.f, 0.f};
        #pragma unroll
        for (int i = 0; i < 4; ++i)
            #pragma unroll
            for (int u = 0; u < 4; ++u) {
                acc[i] = fmaf(w4[i][u].x, h4[u].x, acc[i]);
                acc[i] = fmaf(w4[i][u].y, h4[u].y, acc[i]);
                acc[i] = fmaf(w4[i][u].z, h4[u].z, acc[i]);
                acc[i] = fmaf(w4[i][u].w, h4[u].w, acc[i]);
            }
        // wave-wide butterfly reduce (cols are spread over the 64 lanes)
        #pragma unroll
        for (int off = 32; off >= 1; off >>= 1) {
            #pragma unroll
            for (int i = 0; i < 4; ++i) acc[i] += __shfl_xor(acc[i], off, 64);
        }

        if (l == 0) {
            const int ch   = seq_lds[t & 255];
            const int row0 = b * 16 + wv * 4;
            float4 xp4 = *(const float4*)&XP[(size_t)ch * HID + row0];
            const float xr[4] = {xp4.x, xp4.y, xp4.z, xp4.w};
            u64*   dst   = hbufP + (size_t)((g + 1) & 1) * HID + row0;
            float* hsrow = hs + (size_t)t * HID + row0;
            #pragma unroll
            for (int i = 0; i < 4; ++i) {
                const float hval = tanhf(acc[i] + xr[i]);
                hsrow[i] = hval;
                if (is_last && t == Sc - 1) out_tail[row0 + i] = hval;
                const u64 pk = ((u64)(unsigned)(g + 1) << 32) | (u64)__float_as_uint(hval);
                __hip_atomic_store(dst + i, pk, __ATOMIC_RELAXED, __HIP_MEMORY_SCOPE_SYSTEM);
            }
        }
        // No trailing barrier needed: a thread can only reach step t+1's
        // h_lds write after polling ALL 1024 tags g+1, which are stored only
        // after every wave (incl. ours) finished reading h_lds for step t.
    }
}

// ---------------------------------------------------------------------------
// Kernel 3: out[t][v] = b_y[v] + sum_h Wya[v][h] * hs[t][h]
// f32 LDS-tiled GEMM, 64(t) x 64(v) tile, BK=64, 256 threads, 4x4 micro-tile.
// ---------------------------------------------------------------------------
__global__ __launch_bounds__(256) void out_kernel(
    const float* __restrict__ hs, const float* __restrict__ Wya,
    const float* __restrict__ b_y, float* __restrict__ out, int Sc)
{
    __shared__ float hsT[64][68];
    __shared__ float wyT[64][68];
    const int bx = blockIdx.x;
    const int vt = bx & 7, tt = bx >> 3;
    const int t0 = tt * 64, v0 = vt * 64;
    const int tid = threadIdx.x;
    const int tx = tid & 15, ty = tid >> 4;
    const int r = tid >> 2, cq = tid & 3;

    float acc[4][4] = {};
    for (int k0 = 0; k0 < HID; k0 += 64) {
        #pragma unroll
        for (int j = 0; j < 4; ++j) {
            const int kl = cq * 16 + 4 * j;
            float4 f = *(const float4*)&hs[(size_t)(t0 + r) * HID + k0 + kl];
            hsT[kl + 0][r] = f.x; hsT[kl + 1][r] = f.y;
            hsT[kl + 2][r] = f.z; hsT[kl + 3][r] = f.w;
            float4 g = *(const float4*)&Wya[(size_t)(v0 + r) * HID + k0 + kl];
            wyT[kl + 0][r] = g.x; wyT[kl + 1][r] = g.y;
            wyT[kl + 2][r] = g.z; wyT[kl + 3][r] = g.w;
        }
        __syncthreads();
        #pragma unroll 16
        for (int kk = 0; kk < 64; ++kk) {
            float4 a4 = *(float4*)&hsT[kk][ty * 4];
            float4 b4 = *(float4*)&wyT[kk][tx * 4];
            const float av[4] = {a4.x, a4.y, a4.z, a4.w};
            const float bv[4] = {b4.x, b4.y, b4.z, b4.w};
            #pragma unroll
            for (int m = 0; m < 4; ++m)
                #pragma unroll
                for (int n = 0; n < 4; ++n)
                    acc[m][n] = fmaf(av[m], bv[n], acc[m][n]);
        }
        __syncthreads();
    }
    float4 by4 = *(const float4*)&b_y[v0 + tx * 4];
    const float bb[4] = {by4.x, by4.y, by4.z, by4.w};
    #pragma unroll
    for (int m = 0; m < 4; ++m) {
        float4 o;
        o.x = acc[m][0] + bb[0]; o.y = acc[m][1] + bb[1];
        o.z = acc[m][2] + bb[2]; o.w = acc[m][3] + bb[3];
        *(float4*)&out[(size_t)(t0 + ty * 4 + m) * NCHARS + v0 + tx * 4] = o;
    }
}

// ---------------------------------------------------------------------------
extern "C" void kernel_launch(void* const* d_in, const int* in_sizes, int n_in,
                              void* d_out, int out_size, void* d_ws, size_t ws_size,
                              hipStream_t stream)
{
    const int*   seq = (const int*)d_in[0];
    const float* emb = (const float*)d_in[1];
    const float* Wax = (const float*)d_in[2];
    const float* Waa = (const float*)d_in[3];
    const float* Wya = (const float*)d_in[4];
    const float* b_y = (const float*)d_in[5];
    float* out = (float*)d_out;

    char* ws = (char*)d_ws;
    float* XP    = (float*)ws;                                        // 2 MB
    u64*   hbufP = (u64*)(ws + (size_t)NCHARS * HID * 4);             // 16 KB
    float* hs    = (float*)(ws + (size_t)NCHARS * HID * 4 + 2 * HID * 8);

    const size_t fixed = (size_t)NCHARS * HID * 4 + 2 * HID * 8 + 256;
    int Sc = SEQ_LEN;                       // hs chunk sized to fit the workspace
    while (Sc > 256 && fixed + (size_t)Sc * HID * 4 > ws_size) Sc >>= 1;
    const int C = SEQ_LEN / Sc;

    xp_table_kernel<<<NCHARS / 4, 256, 0, stream>>>(emb, Wax, XP, hbufP);

    float* out_tail = out + (size_t)SEQ_LEN * NCHARS;  // h_last (1024 floats)
    for (int c = 0; c < C; ++c) {
        scan_kernel<<<64, 256, 0, stream>>>(seq, XP, Waa, hbufP, hs,
                                            c * Sc, Sc, out_tail, (c == C - 1) ? 1 : 0);
        out_kernel<<<(Sc / 64) * 8, 256, 0, stream>>>(hs, Wya, b_y,
                                                      out + (size_t)c * Sc * NCHARS, Sc);
    }
}

// Round 2
// 134984.436 us; speedup vs baseline: 1.9264x; 1.9264x over previous
//
#include <hip/hip_runtime.h>
#include <hip/hip_bf16.h>
#include <stdint.h>

#define SEQ_LEN 65536
#define NCHARS  512
#define EMB     512
#define HID     1024
#define NB      64      // scan blocks (producers == consumers)

typedef unsigned long long u64;

__device__ __forceinline__ float fast_tanh(float x) {
    // tanh(x) = 1 - 2/(e^{2x}+1); exact at +-inf, err ~1e-6 mid-range
    float e = __expf(2.0f * x);
    return 1.0f - 2.0f * __builtin_amdgcn_rcpf(e + 1.0f);
}

// ---------------------------------------------------------------------------
// Kernel 1: XP_table[ch][i] = sum_e emb[ch][e] * Wax[i][e]   (512 x 1024)
// ---------------------------------------------------------------------------
__global__ __launch_bounds__(256) void xp_table_kernel(
    const float* __restrict__ emb, const float* __restrict__ Wax,
    float* __restrict__ XP)
{
    __shared__ float elds[4 * EMB];
    const int bx  = blockIdx.x;
    const int tid = threadIdx.x;
    const int ch0 = bx * 4;

    const float4* src = (const float4*)(emb + (size_t)ch0 * EMB);
    float4* dst = (float4*)elds;
    dst[tid]       = src[tid];
    dst[tid + 256] = src[tid + 256];
    __syncthreads();

    float acc[4][4] = {};
    for (int e4 = 0; e4 < EMB / 4; ++e4) {
        float4 ev[4];
        #pragma unroll
        for (int ch = 0; ch < 4; ++ch) ev[ch] = *(const float4*)&elds[ch * EMB + 4 * e4];
        #pragma unroll
        for (int q = 0; q < 4; ++q) {
            const int i = tid + 256 * q;
            float4 w4 = *(const float4*)&Wax[(size_t)i * EMB + 4 * e4];
            #pragma unroll
            for (int ch = 0; ch < 4; ++ch) {
                acc[ch][q] = fmaf(w4.x, ev[ch].x, acc[ch][q]);
                acc[ch][q] = fmaf(w4.y, ev[ch].y, acc[ch][q]);
                acc[ch][q] = fmaf(w4.z, ev[ch].z, acc[ch][q]);
                acc[ch][q] = fmaf(w4.w, ev[ch].w, acc[ch][q]);
            }
        }
    }
    #pragma unroll
    for (int ch = 0; ch < 4; ++ch)
        #pragma unroll
        for (int q = 0; q < 4; ++q)
            XP[(size_t)(ch0 + ch) * HID + tid + 256 * q] = acc[ch][q];
}

// ---------------------------------------------------------------------------
// Kernel 2: sequential scan, 64 blocks x 256 threads.
// Block b owns rows [b*16, b*16+16) of Waa in registers.
// Exchange: per-consumer private mailboxes of tagged {tag|f32} u64 pairs,
//   mail[parity][consumer][row].  Every 64B line is written by exactly ONE
//   producer block and polled by exactly ONE consumer block -> no hot-line
//   contention at the coherence point.  Tag packed with data -> no flag, no
//   ordering fence, no store-ack on the critical path.
// ---------------------------------------------------------------------------
__global__ __launch_bounds__(256) void scan_kernel(
    const int* __restrict__ seq, const float* __restrict__ XP,
    const float* __restrict__ Waa, u64* __restrict__ mail,
    float* __restrict__ hs, int g0, int Sc,
    float* __restrict__ out_tail, int is_last)
{
    __shared__ float h_lds[HID];
    __shared__ float hout[16];
    __shared__ int   seq_lds[256];

    const int b   = blockIdx.x;        // 0..63
    const int tid = threadIdx.x;       // 0..255
    const int l   = tid & 63;
    const int wv  = tid >> 6;
    const int r2  = (l >> 1) & 3;      // float4 rotation for LDS banks

    // Waa slice in registers
    float4 w4[4][4];
    #pragma unroll
    for (int i = 0; i < 4; ++i) {
        const float* wrow = Waa + (size_t)(b * 16 + wv * 4 + i) * HID + l * 16;
        #pragma unroll
        for (int u = 0; u < 4; ++u)
            w4[i][u] = *(const float4*)(wrow + 4 * ((u + r2) & 3));
    }

    // fan-out addressing: thread -> (consumer fc, part fp)
    const int fc = tid >> 2;           // consumer block 0..63
    const int fp = tid & 3;            // which 4 of our 16 rows

    for (int t = 0; t < Sc; ++t) {
        const int g = g0 + t;
        if ((t & 255) == 0) seq_lds[tid] = seq[g + tid];   // g multiple of 256 here

        // ---- poll own mailbox for h_g (rows 4*tid..4*tid+3) ----
        {
            u64* mb = mail + ((size_t)(g & 1) * NB + b) * HID + 4 * tid;
            const unsigned want = (unsigned)g;
            u64 v0, v1, v2, v3;
            do {
                v0 = __hip_atomic_load(mb + 0, __ATOMIC_RELAXED, __HIP_MEMORY_SCOPE_SYSTEM);
                v1 = __hip_atomic_load(mb + 1, __ATOMIC_RELAXED, __HIP_MEMORY_SCOPE_SYSTEM);
                v2 = __hip_atomic_load(mb + 2, __ATOMIC_RELAXED, __HIP_MEMORY_SCOPE_SYSTEM);
                v3 = __hip_atomic_load(mb + 3, __ATOMIC_RELAXED, __HIP_MEMORY_SCOPE_SYSTEM);
            } while (((unsigned)(v0 >> 32) != want) | ((unsigned)(v1 >> 32) != want) |
                     ((unsigned)(v2 >> 32) != want) | ((unsigned)(v3 >> 32) != want));
            float4 hv = make_float4(__uint_as_float((unsigned)v0), __uint_as_float((unsigned)v1),
                                    __uint_as_float((unsigned)v2), __uint_as_float((unsigned)v3));
            *(float4*)&h_lds[4 * tid] = hv;
        }
        __syncthreads();

        // xp gather hoisted: independent of h, overlaps the compute below
        const int ch = seq_lds[t & 255];
        float4 xp4;
        if (l == 0) xp4 = *(const float4*)&XP[(size_t)ch * HID + b * 16 + wv * 4];

        // ---- partial dot products: 4 rows x own 16 cols ----
        float4 h4[4];
        #pragma unroll
        for (int u = 0; u < 4; ++u)
            h4[u] = *(float4*)&h_lds[l * 16 + 4 * ((u + r2) & 3)];
        float acc[4] = {0.f, 0.f, 0.f, 0.f};
        #pragma unroll
        for (int i = 0; i < 4; ++i)
            #pragma unroll
            for (int u = 0; u < 4; ++u) {
                acc[i] = fmaf(w4[i][u].x, h4[u].x, acc[i]);
                acc[i] = fmaf(w4[i][u].y, h4[u].y, acc[i]);
                acc[i] = fmaf(w4[i][u].z, h4[u].z, acc[i]);
                acc[i] = fmaf(w4[i][u].w, h4[u].w, acc[i]);
            }
        #pragma unroll
        for (int off = 32; off >= 1; off >>= 1) {
            #pragma unroll
            for (int i = 0; i < 4; ++i) acc[i] += __shfl_xor(acc[i], off, 64);
        }

        if (l == 0) {
            const int row0 = b * 16 + wv * 4;
            const float xr[4] = {xp4.x, xp4.y, xp4.z, xp4.w};
            float hv[4];
            #pragma unroll
            for (int i = 0; i < 4; ++i) hv[i] = fast_tanh(acc[i] + xr[i]);
            *(float4*)&hs[(size_t)t * HID + row0] = make_float4(hv[0], hv[1], hv[2], hv[3]);
            #pragma unroll
            for (int i = 0; i < 4; ++i) hout[wv * 4 + i] = hv[i];
            if (is_last && t == Sc - 1) {
                #pragma unroll
                for (int i = 0; i < 4; ++i) out_tail[row0 + i] = hv[i];
            }
        }
        __syncthreads();

        // ---- fan out our 16 rows to all 64 consumer mailboxes ----
        {
            const u64 tagp = (u64)(unsigned)(g + 1) << 32;
            u64* dst = mail + ((size_t)((g + 1) & 1) * NB + fc) * HID + b * 16 + fp * 4;
            const float h0 = hout[fp * 4 + 0], h1 = hout[fp * 4 + 1];
            const float h2 = hout[fp * 4 + 2], h3 = hout[fp * 4 + 3];
            __hip_atomic_store(dst + 0, tagp | (u64)__float_as_uint(h0), __ATOMIC_RELAXED, __HIP_MEMORY_SCOPE_SYSTEM);
            __hip_atomic_store(dst + 1, tagp | (u64)__float_as_uint(h1), __ATOMIC_RELAXED, __HIP_MEMORY_SCOPE_SYSTEM);
            __hip_atomic_store(dst + 2, tagp | (u64)__float_as_uint(h2), __ATOMIC_RELAXED, __HIP_MEMORY_SCOPE_SYSTEM);
            __hip_atomic_store(dst + 3, tagp | (u64)__float_as_uint(h3), __ATOMIC_RELAXED, __HIP_MEMORY_SCOPE_SYSTEM);
        }
        // No trailing barrier: a thread reaches step t+1's h_lds write only
        // after its poll sees tags g+1, which requires every block (incl.
        // ours) to have finished step t's barriers and fan-out.
    }
}

// ---------------------------------------------------------------------------
// Kernel 3: out[t][v] = b_y[v] + sum_h Wya[v][h] * hs[t][h]
// ---------------------------------------------------------------------------
__global__ __launch_bounds__(256) void out_kernel(
    const float* __restrict__ hs, const float* __restrict__ Wya,
    const float* __restrict__ b_y, float* __restrict__ out, int Sc)
{
    __shared__ float hsT[64][68];
    __shared__ float wyT[64][68];
    const int bx = blockIdx.x;
    const int vt = bx & 7, tt = bx >> 3;
    const int t0 = tt * 64, v0 = vt * 64;
    const int tid = threadIdx.x;
    const int tx = tid & 15, ty = tid >> 4;
    const int r = tid >> 2, cq = tid & 3;

    float acc[4][4] = {};
    for (int k0 = 0; k0 < HID; k0 += 64) {
        #pragma unroll
        for (int j = 0; j < 4; ++j) {
            const int kl = cq * 16 + 4 * j;
            float4 f = *(const float4*)&hs[(size_t)(t0 + r) * HID + k0 + kl];
            hsT[kl + 0][r] = f.x; hsT[kl + 1][r] = f.y;
            hsT[kl + 2][r] = f.z; hsT[kl + 3][r] = f.w;
            float4 g = *(const float4*)&Wya[(size_t)(v0 + r) * HID + k0 + kl];
            wyT[kl + 0][r] = g.x; wyT[kl + 1][r] = g.y;
            wyT[kl + 2][r] = g.z; wyT[kl + 3][r] = g.w;
        }
        __syncthreads();
        #pragma unroll 16
        for (int kk = 0; kk < 64; ++kk) {
            float4 a4 = *(float4*)&hsT[kk][ty * 4];
            float4 b4 = *(float4*)&wyT[kk][tx * 4];
            const float av[4] = {a4.x, a4.y, a4.z, a4.w};
            const float bv[4] = {b4.x, b4.y, b4.z, b4.w};
            #pragma unroll
            for (int m = 0; m < 4; ++m)
                #pragma unroll
                for (int n = 0; n < 4; ++n)
                    acc[m][n] = fmaf(av[m], bv[n], acc[m][n]);
        }
        __syncthreads();
    }
    float4 by4 = *(const float4*)&b_y[v0 + tx * 4];
    const float bb[4] = {by4.x, by4.y, by4.z, by4.w};
    #pragma unroll
    for (int m = 0; m < 4; ++m) {
        float4 o;
        o.x = acc[m][0] + bb[0]; o.y = acc[m][1] + bb[1];
        o.z = acc[m][2] + bb[2]; o.w = acc[m][3] + bb[3];
        *(float4*)&out[(size_t)(t0 + ty * 4 + m) * NCHARS + v0 + tx * 4] = o;
    }
}

// ---------------------------------------------------------------------------
extern "C" void kernel_launch(void* const* d_in, const int* in_sizes, int n_in,
                              void* d_out, int out_size, void* d_ws, size_t ws_size,
                              hipStream_t stream)
{
    const int*   seq = (const int*)d_in[0];
    const float* emb = (const float*)d_in[1];
    const float* Wax = (const float*)d_in[2];
    const float* Waa = (const float*)d_in[3];
    const float* Wya = (const float*)d_in[4];
    const float* b_y = (const float*)d_in[5];
    float* out = (float*)d_out;

    const size_t XP_BYTES   = (size_t)NCHARS * HID * 4;        // 2 MB
    const size_t MAIL_BYTES = (size_t)2 * NB * HID * 8;        // 1 MB

    char* ws = (char*)d_ws;
    float* XP   = (float*)ws;
    u64*   mail = (u64*)(ws + XP_BYTES);
    float* hs   = (float*)(ws + XP_BYTES + MAIL_BYTES);

    const size_t fixed = XP_BYTES + MAIL_BYTES + 256;
    int Sc = SEQ_LEN;
    while (Sc > 256 && fixed + (size_t)Sc * HID * 4 > ws_size) Sc >>= 1;
    const int C = SEQ_LEN / Sc;

    // parity-0 mailboxes <- tag 0 | h_0 = 0  (ws is poisoned 0xAA each call;
    // poison tags 0xAAAAAAAA never match a wanted tag)
    hipMemsetAsync(mail, 0, (size_t)NB * HID * 8, stream);
    xp_table_kernel<<<NCHARS / 4, 256, 0, stream>>>(emb, Wax, XP);

    float* out_tail = out + (size_t)SEQ_LEN * NCHARS;  // h_last
    for (int c = 0; c < C; ++c) {
        scan_kernel<<<NB, 256, 0, stream>>>(seq, XP, Waa, mail, hs,
                                            c * Sc, Sc, out_tail, (c == C - 1) ? 1 : 0);
        out_kernel<<<(Sc / 64) * 8, 256, 0, stream>>>(hs, Wya, b_y,
                                                      out + (size_t)c * Sc * NCHARS, Sc);
    }
}

// Round 5
// 127267.676 us; speedup vs baseline: 2.0432x; 1.0606x over previous
//
#include <hip/hip_runtime.h>
#include <hip/hip_bf16.h>
#include <stdint.h>

#define SEQ_LEN 65536
#define NCHARS  512
#define EMB     512
#define HID     1024
#define NB      64      // scan blocks (producers == consumers)

typedef unsigned long long u64;
typedef unsigned int u32x4 __attribute__((ext_vector_type(4)));  // native vec -> "v" asm constraint OK

__device__ __forceinline__ float fast_tanh(float x) {
    // tanh(x) = 1 - 2/(e^{2x}+1); exact at +-inf, err ~1e-6 mid-range
    float e = __expf(2.0f * x);
    return 1.0f - 2.0f * __builtin_amdgcn_rcpf(e + 1.0f);
}

// ---------------------------------------------------------------------------
// Kernel 1: XP_table[ch][i] = sum_e emb[ch][e] * Wax[i][e]   (512 x 1024)
// ---------------------------------------------------------------------------
__global__ __launch_bounds__(256) void xp_table_kernel(
    const float* __restrict__ emb, const float* __restrict__ Wax,
    float* __restrict__ XP)
{
    __shared__ float elds[4 * EMB];
    const int bx  = blockIdx.x;
    const int tid = threadIdx.x;
    const int ch0 = bx * 4;

    const float4* src = (const float4*)(emb + (size_t)ch0 * EMB);
    float4* dst = (float4*)elds;
    dst[tid]       = src[tid];
    dst[tid + 256] = src[tid + 256];
    __syncthreads();

    float acc[4][4] = {};
    for (int e4 = 0; e4 < EMB / 4; ++e4) {
        float4 ev[4];
        #pragma unroll
        for (int ch = 0; ch < 4; ++ch) ev[ch] = *(const float4*)&elds[ch * EMB + 4 * e4];
        #pragma unroll
        for (int q = 0; q < 4; ++q) {
            const int i = tid + 256 * q;
            float4 w4 = *(const float4*)&Wax[(size_t)i * EMB + 4 * e4];
            #pragma unroll
            for (int ch = 0; ch < 4; ++ch) {
                acc[ch][q] = fmaf(w4.x, ev[ch].x, acc[ch][q]);
                acc[ch][q] = fmaf(w4.y, ev[ch].y, acc[ch][q]);
                acc[ch][q] = fmaf(w4.z, ev[ch].z, acc[ch][q]);
                acc[ch][q] = fmaf(w4.w, ev[ch].w, acc[ch][q]);
            }
        }
    }
    #pragma unroll
    for (int ch = 0; ch < 4; ++ch)
        #pragma unroll
        for (int q = 0; q < 4; ++q)
            XP[(size_t)(ch0 + ch) * HID + tid + 256 * q] = acc[ch][q];
}

// ---------------------------------------------------------------------------
// Kernel 2: sequential scan, 64 blocks x 256 threads.
// Block b owns rows [b*16, b*16+16) of Waa in registers.
// Exchange: per-consumer private mailboxes of tagged {tag|f32} u64 pairs,
//   mail[parity][consumer][row].  All mailbox traffic is line-coalesced:
//   - fan-out: 2 x 16B dwordx4 stores (sc0 sc1), lanes 0..7 cover one
//     consumer's full 128B region -> full-line writes, no partial-line RMW.
//     Each u64 half carries its own tag, so 8B tearing is harmless.
//   - poll: 4 x 8B atomic loads at row = tid + 256k (lane-contiguous).
// Tag packed with data -> no flag, no fence, no store-ack on critical path.
// ---------------------------------------------------------------------------
__global__ __launch_bounds__(256) void scan_kernel(
    const int* __restrict__ seq, const float* __restrict__ XP,
    const float* __restrict__ Waa, u64* __restrict__ mail,
    float* __restrict__ hs, int g0, int Sc,
    float* __restrict__ out_tail, int is_last)
{
    __shared__ float h_lds[HID];
    __shared__ float hout[16];
    __shared__ int   seq_lds[256];

    const int b   = blockIdx.x;        // 0..63
    const int tid = threadIdx.x;       // 0..255
    const int l   = tid & 63;
    const int wv  = tid >> 6;
    const int r2  = (l >> 1) & 3;      // float4 rotation for LDS banks

    // Waa slice in registers
    float4 w4[4][4];
    #pragma unroll
    for (int i = 0; i < 4; ++i) {
        const float* wrow = Waa + (size_t)(b * 16 + wv * 4 + i) * HID + l * 16;
        #pragma unroll
        for (int u = 0; u < 4; ++u)
            w4[i][u] = *(const float4*)(wrow + 4 * ((u + r2) & 3));
    }

    // fan-out addressing (16B stores): instr k in {0,1}:
    //   consumer fc_k = k*32 + (tid>>3), rows 2j,2j+1 with j = tid&7
    const int fj  = tid & 7;
    const int fc0 = (tid >> 3);        // + k*32

    for (int t = 0; t < Sc; ++t) {
        const int g = g0 + t;
        if ((t & 255) == 0) seq_lds[tid] = seq[g + tid];   // g multiple of 256 here

        // ---- poll own mailbox for h_g: rows tid + 256k (lane-contiguous) ----
        {
            u64* mb = mail + ((size_t)(g & 1) * NB + b) * HID + tid;
            const unsigned want = (unsigned)g;
            u64 v0, v1, v2, v3;
            do {
                v0 = __hip_atomic_load(mb + 0,   __ATOMIC_RELAXED, __HIP_MEMORY_SCOPE_SYSTEM);
                v1 = __hip_atomic_load(mb + 256, __ATOMIC_RELAXED, __HIP_MEMORY_SCOPE_SYSTEM);
                v2 = __hip_atomic_load(mb + 512, __ATOMIC_RELAXED, __HIP_MEMORY_SCOPE_SYSTEM);
                v3 = __hip_atomic_load(mb + 768, __ATOMIC_RELAXED, __HIP_MEMORY_SCOPE_SYSTEM);
            } while (((unsigned)(v0 >> 32) != want) | ((unsigned)(v1 >> 32) != want) |
                     ((unsigned)(v2 >> 32) != want) | ((unsigned)(v3 >> 32) != want));
            h_lds[tid +   0] = __uint_as_float((unsigned)v0);
            h_lds[tid + 256] = __uint_as_float((unsigned)v1);
            h_lds[tid + 512] = __uint_as_float((unsigned)v2);
            h_lds[tid + 768] = __uint_as_float((unsigned)v3);
        }
        __syncthreads();

        // xp gather (independent of h, overlaps compute)
        const int ch = seq_lds[t & 255];
        float4 xp4;
        if (l == 0) xp4 = *(const float4*)&XP[(size_t)ch * HID + b * 16 + wv * 4];

        // ---- partial dot products: 4 rows x own 16 cols ----
        float4 h4[4];
        #pragma unroll
        for (int u = 0; u < 4; ++u)
            h4[u] = *(float4*)&h_lds[l * 16 + 4 * ((u + r2) & 3)];
        float acc[4] = {0.f, 0.f, 0.f, 0.f};
        #pragma unroll
        for (int i = 0; i < 4; ++i)
            #pragma unroll
            for (int u = 0; u < 4; ++u) {
                acc[i] = fmaf(w4[i][u].x, h4[u].x, acc[i]);
                acc[i] = fmaf(w4[i][u].y, h4[u].y, acc[i]);
                acc[i] = fmaf(w4[i][u].z, h4[u].z, acc[i]);
                acc[i] = fmaf(w4[i][u].w, h4[u].w, acc[i]);
            }
        #pragma unroll
        for (int off = 32; off >= 1; off >>= 1) {
            #pragma unroll
            for (int i = 0; i < 4; ++i) acc[i] += __shfl_xor(acc[i], off, 64);
        }

        if (l == 0) {
            const int row0 = b * 16 + wv * 4;
            const float xr[4] = {xp4.x, xp4.y, xp4.z, xp4.w};
            float hv[4];
            #pragma unroll
            for (int i = 0; i < 4; ++i) hv[i] = fast_tanh(acc[i] + xr[i]);
            *(float4*)&hs[(size_t)t * HID + row0] = make_float4(hv[0], hv[1], hv[2], hv[3]);
            #pragma unroll
            for (int i = 0; i < 4; ++i) hout[wv * 4 + i] = hv[i];
            if (is_last && t == Sc - 1) {
                #pragma unroll
                for (int i = 0; i < 4; ++i) out_tail[row0 + i] = hv[i];
            }
        }
        __syncthreads();

        // ---- fan out: 2 x 16B full-line-coalesced stores per thread ----
        {
            const unsigned tag = (unsigned)(g + 1);
            u32x4 pk;
            pk.x = __float_as_uint(hout[2 * fj + 0]); pk.y = tag;
            pk.z = __float_as_uint(hout[2 * fj + 1]); pk.w = tag;
            u64* base = mail + (size_t)((g + 1) & 1) * NB * HID + (size_t)b * 16 + 2 * fj;
            const u64 addrA = (u64)(base + (size_t)(fc0     ) * HID);
            const u64 addrB = (u64)(base + (size_t)(fc0 + 32) * HID);
            asm volatile("global_store_dwordx4 %0, %1, off sc0 sc1"
                         :: "v"(addrA), "v"(pk) : "memory");
            asm volatile("global_store_dwordx4 %0, %1, off sc0 sc1"
                         :: "v"(addrB), "v"(pk) : "memory");
        }
        // No trailing barrier: a thread reaches step t+1's h_lds write only
        // after its poll sees tags g+1, which requires every block (incl.
        // ours) to have finished step t's barriers and fan-out.
    }
}

// ---------------------------------------------------------------------------
// Kernel 3: out[t][v] = b_y[v] + sum_h Wya[v][h] * hs[t][h]
// ---------------------------------------------------------------------------
__global__ __launch_bounds__(256) void out_kernel(
    const float* __restrict__ hs, const float* __restrict__ Wya,
    const float* __restrict__ b_y, float* __restrict__ out, int Sc)
{
    __shared__ float hsT[64][68];
    __shared__ float wyT[64][68];
    const int bx = blockIdx.x;
    const int vt = bx & 7, tt = bx >> 3;
    const int t0 = tt * 64, v0 = vt * 64;
    const int tid = threadIdx.x;
    const int tx = tid & 15, ty = tid >> 4;
    const int r = tid >> 2, cq = tid & 3;

    float acc[4][4] = {};
    for (int k0 = 0; k0 < HID; k0 += 64) {
        #pragma unroll
        for (int j = 0; j < 4; ++j) {
            const int kl = cq * 16 + 4 * j;
            float4 f = *(const float4*)&hs[(size_t)(t0 + r) * HID + k0 + kl];
            hsT[kl + 0][r] = f.x; hsT[kl + 1][r] = f.y;
            hsT[kl + 2][r] = f.z; hsT[kl + 3][r] = f.w;
            float4 g = *(const float4*)&Wya[(size_t)(v0 + r) * HID + k0 + kl];
            wyT[kl + 0][r] = g.x; wyT[kl + 1][r] = g.y;
            wyT[kl + 2][r] = g.z; wyT[kl + 3][r] = g.w;
        }
        __syncthreads();
        #pragma unroll 16
        for (int kk = 0; kk < 64; ++kk) {
            float4 a4 = *(float4*)&hsT[kk][ty * 4];
            float4 b4 = *(float4*)&wyT[kk][tx * 4];
            const float av[4] = {a4.x, a4.y, a4.z, a4.w};
            const float bv[4] = {b4.x, b4.y, b4.z, b4.w};
            #pragma unroll
            for (int m = 0; m < 4; ++m)
                #pragma unroll
                for (int n = 0; n < 4; ++n)
                    acc[m][n] = fmaf(av[m], bv[n], acc[m][n]);
        }
        __syncthreads();
    }
    float4 by4 = *(const float4*)&b_y[v0 + tx * 4];
    const float bb[4] = {by4.x, by4.y, by4.z, by4.w};
    #pragma unroll
    for (int m = 0; m < 4; ++m) {
        float4 o;
        o.x = acc[m][0] + bb[0]; o.y = acc[m][1] + bb[1];
        o.z = acc[m][2] + bb[2]; o.w = acc[m][3] + bb[3];
        *(float4*)&out[(size_t)(t0 + ty * 4 + m) * NCHARS + v0 + tx * 4] = o;
    }
}

// ---------------------------------------------------------------------------
extern "C" void kernel_launch(void* const* d_in, const int* in_sizes, int n_in,
                              void* d_out, int out_size, void* d_ws, size_t ws_size,
                              hipStream_t stream)
{
    const int*   seq = (const int*)d_in[0];
    const float* emb = (const float*)d_in[1];
    const float* Wax = (const float*)d_in[2];
    const float* Waa = (const float*)d_in[3];
    const float* Wya = (const float*)d_in[4];
    const float* b_y = (const float*)d_in[5];
    float* out = (float*)d_out;

    const size_t XP_BYTES   = (size_t)NCHARS * HID * 4;        // 2 MB
    const size_t MAIL_BYTES = (size_t)2 * NB * HID * 8;        // 1 MB

    char* ws = (char*)d_ws;
    float* XP   = (float*)ws;
    u64*   mail = (u64*)(ws + XP_BYTES);
    float* hs   = (float*)(ws + XP_BYTES + MAIL_BYTES);

    const size_t fixed = XP_BYTES + MAIL_BYTES + 256;
    int Sc = SEQ_LEN;
    while (Sc > 256 && fixed + (size_t)Sc * HID * 4 > ws_size) Sc >>= 1;
    const int C = SEQ_LEN / Sc;

    // parity-0 mailboxes <- tag 0 | h_0 = 0  (ws re-poisoned 0xAA each call;
    // poison tags never match a wanted tag)
    (void)hipMemsetAsync(mail, 0, (size_t)NB * HID * 8, stream);
    xp_table_kernel<<<NCHARS / 4, 256, 0, stream>>>(emb, Wax, XP);

    float* out_tail = out + (size_t)SEQ_LEN * NCHARS;  // h_last
    for (int c = 0; c < C; ++c) {
        scan_kernel<<<NB, 256, 0, stream>>>(seq, XP, Waa, mail, hs,
                                            c * Sc, Sc, out_tail, (c == C - 1) ? 1 : 0);
        out_kernel<<<(Sc / 64) * 8, 256, 0, stream>>>(hs, Wya, b_y,
                                                      out + (size_t)c * Sc * NCHARS, Sc);
    }
}